// Round 1
// baseline (1509.229 us; speedup 1.0000x reference)
//
#include <hip/hip_runtime.h>
#include <math.h>

#define F_IN 128
#define H_DIM 256
#define C_OUT 40

// ---------------------------------------------------------------------------
// Kernel 1: agg = (1 + eps) * x      (vectorized float4)
// ---------------------------------------------------------------------------
__global__ __launch_bounds__(256) void init_agg(const float* __restrict__ x,
                                                const float* __restrict__ epsp,
                                                float* __restrict__ agg, int n4) {
    int i = blockIdx.x * 256 + threadIdx.x;
    if (i >= n4) return;
    float s = 1.0f + epsp[0];
    float4 v = reinterpret_cast<const float4*>(x)[i];
    reinterpret_cast<float4*>(agg)[i] = make_float4(v.x * s, v.y * s, v.z * s, v.w * s);
}

// ---------------------------------------------------------------------------
// Kernel 2: agg[dst] += x[src] for each edge (32 threads per edge, float4 each)
// ---------------------------------------------------------------------------
__global__ __launch_bounds__(256) void scatter_add(const float* __restrict__ x,
                                                   const int* __restrict__ srcIdx,
                                                   const int* __restrict__ dstIdx,
                                                   float* __restrict__ agg, int E) {
    int t = blockIdx.x * 256 + threadIdx.x;
    if (t >= E * 32) return;
    int e = t >> 5;
    int c = t & 31;
    int s = srcIdx[e];
    int d = dstIdx[e];
    float4 v = *reinterpret_cast<const float4*>(x + (size_t)s * F_IN + c * 4);
    float* a = agg + (size_t)d * F_IN + c * 4;
    atomicAdd(a + 0, v.x);
    atomicAdd(a + 1, v.y);
    atomicAdd(a + 2, v.z);
    atomicAdd(a + 3, v.w);
}

// ---------------------------------------------------------------------------
// Kernel 3: h1T[col][row] = relu(agg[row,:] @ W1[:,col] + b1[col])
// fp32 tiled GEMM: M=N(50000), K=128, N=256. BM=BN=64, BK=32, 256 thr, 4x4/thr.
// Writes TRANSPOSED output [H_DIM][N] for coalesced downstream access.
// ---------------------------------------------------------------------------
#define BM 64
#define BN 64
#define BK 32
__global__ __launch_bounds__(256) void gemm1(const float* __restrict__ A,
                                             const float* __restrict__ W1,
                                             const float* __restrict__ b1,
                                             float* __restrict__ h1T, int N) {
    __shared__ float As[BK][BM + 4];  // transposed A tile; row stride 68 floats (16B aligned)
    __shared__ float Bs[BK][BN];

    int tid = threadIdx.x;
    int tx = tid & 15;       // 0..15 -> 4 cols each
    int ty = tid >> 4;       // 0..15 -> 4 rows each
    int m0 = blockIdx.x * BM;
    int n0 = blockIdx.y * BN;

    float acc[4][4] = {};

    for (int k0 = 0; k0 < F_IN; k0 += BK) {
        // load A tile: 64 rows x 32 cols = 512 float4, 2 per thread, coalesced
        #pragma unroll
        for (int l = 0; l < 2; ++l) {
            int i = tid + l * 256;
            int row = i >> 3;      // /8 float4 per row
            int c4 = i & 7;
            float4 v = make_float4(0.f, 0.f, 0.f, 0.f);
            int gr = m0 + row;
            if (gr < N) v = *reinterpret_cast<const float4*>(A + (size_t)gr * F_IN + k0 + c4 * 4);
            As[c4 * 4 + 0][row] = v.x;
            As[c4 * 4 + 1][row] = v.y;
            As[c4 * 4 + 2][row] = v.z;
            As[c4 * 4 + 3][row] = v.w;
        }
        // load B tile: 32 rows x 64 cols = 512 float4, 2 per thread, coalesced
        #pragma unroll
        for (int l = 0; l < 2; ++l) {
            int i = tid + l * 256;
            int row = i >> 4;      // /16 float4 per row
            int c4 = i & 15;
            *reinterpret_cast<float4*>(&Bs[row][c4 * 4]) =
                *reinterpret_cast<const float4*>(W1 + (size_t)(k0 + row) * H_DIM + n0 + c4 * 4);
        }
        __syncthreads();

        #pragma unroll
        for (int k = 0; k < BK; ++k) {
            float4 a4 = *reinterpret_cast<const float4*>(&As[k][ty * 4]);
            float4 b4 = *reinterpret_cast<const float4*>(&Bs[k][tx * 4]);
            float a[4] = {a4.x, a4.y, a4.z, a4.w};
            float b[4] = {b4.x, b4.y, b4.z, b4.w};
            #pragma unroll
            for (int r = 0; r < 4; ++r)
                #pragma unroll
                for (int c = 0; c < 4; ++c)
                    acc[r][c] = fmaf(a[r], b[c], acc[r][c]);
        }
        __syncthreads();
    }

    // epilogue: bias + relu, store transposed (column-major h1T[col*N + row])
    float4 bias = *reinterpret_cast<const float4*>(b1 + n0 + tx * 4);
    float bv[4] = {bias.x, bias.y, bias.z, bias.w};
    int row0 = m0 + ty * 4;
    #pragma unroll
    for (int c = 0; c < 4; ++c) {
        float4 v;
        v.x = fmaxf(acc[0][c] + bv[c], 0.f);
        v.y = fmaxf(acc[1][c] + bv[c], 0.f);
        v.z = fmaxf(acc[2][c] + bv[c], 0.f);
        v.w = fmaxf(acc[3][c] + bv[c], 0.f);
        size_t base = (size_t)(n0 + tx * 4 + c) * N;
        if (row0 + 3 < N) {
            *reinterpret_cast<float4*>(h1T + base + row0) = v;
        } else {
            float vv[4] = {v.x, v.y, v.z, v.w};
            for (int r = 0; r < 4; ++r)
                if (row0 + r < N) h1T[base + row0 + r] = vv[r];
        }
    }
}

// ---------------------------------------------------------------------------
// Kernel 4: per-column sum & sumsq over N rows (one block per hidden column)
// ---------------------------------------------------------------------------
__global__ __launch_bounds__(256) void bn_stats(const float* __restrict__ h1T,
                                                float* __restrict__ sums,
                                                float* __restrict__ sumsq, int N) {
    __shared__ float red[8];
    int k = blockIdx.x;
    const float* col = h1T + (size_t)k * N;
    float s = 0.f, ss = 0.f;
    for (int i = threadIdx.x; i < N; i += 256) {
        float v = col[i];
        s += v;
        ss = fmaf(v, v, ss);
    }
    #pragma unroll
    for (int off = 32; off > 0; off >>= 1) {
        s += __shfl_down(s, off, 64);
        ss += __shfl_down(ss, off, 64);
    }
    int wave = threadIdx.x >> 6;
    int lane = threadIdx.x & 63;
    if (lane == 0) { red[wave] = s; red[4 + wave] = ss; }
    __syncthreads();
    if (threadIdx.x == 0) {
        float st = red[0] + red[1] + red[2] + red[3];
        float sst = red[4] + red[5] + red[6] + red[7];
        sums[k] = st;
        sumsq[k] = sst;
    }
}

// ---------------------------------------------------------------------------
// Kernel 5: fold BN into W2/b2:  W2f = scale*W2 ; b2f = b2 + shift @ W2
// ---------------------------------------------------------------------------
__global__ __launch_bounds__(256) void bn_fold(const float* __restrict__ sums,
                                               const float* __restrict__ sumsq,
                                               const float* __restrict__ gamma,
                                               const float* __restrict__ beta,
                                               const float* __restrict__ W2,
                                               const float* __restrict__ b2,
                                               float* __restrict__ W2f,
                                               float* __restrict__ b2f, int N) {
    __shared__ float shift_s[H_DIM];
    int k = threadIdx.x;
    float invN = 1.0f / (float)N;
    float mean = sums[k] * invN;
    float var = sumsq[k] * invN - mean * mean;
    float scale = gamma[k] * rsqrtf(var + 1e-5f);
    float shift = beta[k] - mean * scale;
    shift_s[k] = shift;
    #pragma unroll
    for (int c = 0; c < C_OUT; ++c) W2f[k * C_OUT + c] = scale * W2[k * C_OUT + c];
    __syncthreads();
    if (k < C_OUT) {
        float acc = b2[k];
        for (int j = 0; j < H_DIM; ++j) acc = fmaf(shift_s[j], W2[j * C_OUT + k], acc);
        b2f[k] = acc;
    }
}

// ---------------------------------------------------------------------------
// Kernel 6: out[row,:] = log_softmax(h1T[:,row] @ W2f + b2f)
// Thread-per-row; W2f reads are block-uniform -> scalar loads; 40 acc regs.
// ---------------------------------------------------------------------------
__global__ __launch_bounds__(64) void gemm2_lsm(const float* __restrict__ h1T,
                                                const float* __restrict__ W2f,
                                                const float* __restrict__ b2f,
                                                float* __restrict__ out, int N) {
    int row = blockIdx.x * 64 + threadIdx.x;
    int r = row < N ? row : N - 1;
    float acc[C_OUT];
    #pragma unroll
    for (int c = 0; c < C_OUT; ++c) acc[c] = b2f[c];

    const float* hp = h1T + r;
    for (int k = 0; k < H_DIM; k += 8) {
        float h[8];
        #pragma unroll
        for (int kk = 0; kk < 8; ++kk) h[kk] = hp[(size_t)(k + kk) * N];
        #pragma unroll
        for (int kk = 0; kk < 8; ++kk) {
            const float4* w = reinterpret_cast<const float4*>(W2f + (k + kk) * C_OUT);
            #pragma unroll
            for (int q = 0; q < 10; ++q) {
                float4 wv = w[q];
                acc[q * 4 + 0] = fmaf(h[kk], wv.x, acc[q * 4 + 0]);
                acc[q * 4 + 1] = fmaf(h[kk], wv.y, acc[q * 4 + 1]);
                acc[q * 4 + 2] = fmaf(h[kk], wv.z, acc[q * 4 + 2]);
                acc[q * 4 + 3] = fmaf(h[kk], wv.w, acc[q * 4 + 3]);
            }
        }
    }
    // fused log_softmax
    float m = acc[0];
    #pragma unroll
    for (int c = 1; c < C_OUT; ++c) m = fmaxf(m, acc[c]);
    float s = 0.f;
    #pragma unroll
    for (int c = 0; c < C_OUT; ++c) s += __expf(acc[c] - m);
    float lse = m + __logf(s);
    if (row < N) {
        float4* op = reinterpret_cast<float4*>(out + (size_t)row * C_OUT);
        #pragma unroll
        for (int q = 0; q < 10; ++q) {
            op[q] = make_float4(acc[q * 4 + 0] - lse, acc[q * 4 + 1] - lse,
                                acc[q * 4 + 2] - lse, acc[q * 4 + 3] - lse);
        }
    }
}

// ---------------------------------------------------------------------------
extern "C" void kernel_launch(void* const* d_in, const int* in_sizes, int n_in,
                              void* d_out, int out_size, void* d_ws, size_t ws_size,
                              hipStream_t stream) {
    const float* x     = (const float*)d_in[0];
    const int*   ei    = (const int*)d_in[1];
    const float* eps   = (const float*)d_in[2];
    const float* W1    = (const float*)d_in[3];
    const float* b1    = (const float*)d_in[4];
    const float* gamma = (const float*)d_in[5];
    const float* beta  = (const float*)d_in[6];
    const float* W2    = (const float*)d_in[7];
    const float* b2    = (const float*)d_in[8];
    float* out = (float*)d_out;

    int N = in_sizes[0] / F_IN;   // 50000
    int E = in_sizes[1] / 2;      // 800000
    const int* srcIdx = ei;       // edge_index[0]
    const int* dstIdx = ei + E;   // edge_index[1]

    float* ws    = (float*)d_ws;
    float* agg   = ws;                                  // N*128
    float* h1T   = agg + (size_t)N * F_IN;              // 256*N (transposed)
    float* sums  = h1T + (size_t)H_DIM * N;             // 256
    float* sumsq = sums + H_DIM;                        // 256
    float* W2f   = sumsq + H_DIM;                       // 256*40
    float* b2f   = W2f + H_DIM * C_OUT;                 // 40

    int n4 = N * F_IN / 4;
    hipLaunchKernelGGL(init_agg, dim3((n4 + 255) / 256), dim3(256), 0, stream, x, eps, agg, n4);

    long long tot = (long long)E * 32;
    hipLaunchKernelGGL(scatter_add, dim3((unsigned)((tot + 255) / 256)), dim3(256), 0, stream,
                       x, srcIdx, dstIdx, agg, E);

    dim3 g1((N + BM - 1) / BM, H_DIM / BN);
    hipLaunchKernelGGL(gemm1, g1, dim3(256), 0, stream, agg, W1, b1, h1T, N);

    hipLaunchKernelGGL(bn_stats, dim3(H_DIM), dim3(256), 0, stream, h1T, sums, sumsq, N);

    hipLaunchKernelGGL(bn_fold, dim3(1), dim3(H_DIM), 0, stream,
                       sums, sumsq, gamma, beta, W2, b2, W2f, b2f, N);

    hipLaunchKernelGGL(gemm2_lsm, dim3((N + 63) / 64), dim3(64), 0, stream, h1T, W2f, b2f, out, N);
}

// Round 2
// 343.356 us; speedup vs baseline: 4.3955x; 4.3955x over previous
//
#include <hip/hip_runtime.h>
#include <math.h>

#define F_IN 128
#define H_DIM 256
#define C_OUT 40

// ---------------------------------------------------------------------------
// Kernel: zero an int array
// ---------------------------------------------------------------------------
__global__ __launch_bounds__(256) void zero_int(int* __restrict__ p, int n) {
    int i = blockIdx.x * 256 + threadIdx.x;
    if (i < n) p[i] = 0;
}

// ---------------------------------------------------------------------------
// Kernel: degree histogram over dst
// ---------------------------------------------------------------------------
__global__ __launch_bounds__(256) void hist_deg(const int* __restrict__ dst,
                                                int* __restrict__ deg, int E) {
    int i = blockIdx.x * 256 + threadIdx.x;
    if (i < E) atomicAdd(&deg[dst[i]], 1);
}

// ---------------------------------------------------------------------------
// Kernel: single-block exclusive scan of deg -> row_ptr (N+1) and cursor (N)
// 1024 threads, 4 elements/thread/chunk (4096 per iteration)
// ---------------------------------------------------------------------------
__global__ __launch_bounds__(1024) void scan_deg(const int* __restrict__ deg,
                                                 int* __restrict__ row_ptr,
                                                 int* __restrict__ cursor, int N) {
    __shared__ int wsum[16];
    __shared__ int s_carry;
    if (threadIdx.x == 0) { s_carry = 0; row_ptr[0] = 0; }
    __syncthreads();
    int lane = threadIdx.x & 63;
    int wv = threadIdx.x >> 6;
    for (int base = 0; base < N; base += 4096) {
        int i0 = base + (int)threadIdx.x * 4;
        int4 v = make_int4(0, 0, 0, 0);
        if (i0 + 3 < N) {
            v = *reinterpret_cast<const int4*>(deg + i0);
        } else {
            if (i0 + 0 < N) v.x = deg[i0 + 0];
            if (i0 + 1 < N) v.y = deg[i0 + 1];
            if (i0 + 2 < N) v.z = deg[i0 + 2];
            if (i0 + 3 < N) v.w = deg[i0 + 3];
        }
        int tsum = v.x + v.y + v.z + v.w;
        int sc = tsum;
        #pragma unroll
        for (int o = 1; o < 64; o <<= 1) {
            int t = __shfl_up(sc, o, 64);
            if (lane >= o) sc += t;
        }
        if (lane == 63) wsum[wv] = sc;
        __syncthreads();
        if (threadIdx.x < 16) {
            int s = wsum[threadIdx.x];
            #pragma unroll
            for (int o = 1; o < 16; o <<= 1) {
                int t = __shfl_up(s, o, 16);
                if ((int)threadIdx.x >= o) s += t;
            }
            wsum[threadIdx.x] = s;
        }
        __syncthreads();
        int carry = s_carry;
        int woff = (wv > 0) ? wsum[wv - 1] : 0;
        int p0 = carry + woff + sc - tsum;  // exclusive prefix of element i0
        int q0 = p0 + v.x;
        int q1 = q0 + v.y;
        int q2 = q1 + v.z;
        int q3 = q2 + v.w;
        if (i0 < N) {
            if (i0 + 3 < N) {
                *reinterpret_cast<int4*>(cursor + i0) = make_int4(p0, q0, q1, q2);
            } else {
                cursor[i0] = p0;
                if (i0 + 1 < N) cursor[i0 + 1] = q0;
                if (i0 + 2 < N) cursor[i0 + 2] = q1;
            }
            if (i0 + 0 < N) row_ptr[i0 + 1] = q0;
            if (i0 + 1 < N) row_ptr[i0 + 2] = q1;
            if (i0 + 2 < N) row_ptr[i0 + 3] = q2;
            if (i0 + 3 < N) row_ptr[i0 + 4] = q3;
        }
        int chunk_total = wsum[15];
        __syncthreads();
        if (threadIdx.x == 0) s_carry = carry + chunk_total;
        __syncthreads();
    }
}

// ---------------------------------------------------------------------------
// Kernel: fill CSR adjacency (edge_src grouped by dst)
// ---------------------------------------------------------------------------
__global__ __launch_bounds__(256) void fill_csr(const int* __restrict__ src,
                                                const int* __restrict__ dst,
                                                int* __restrict__ cursor,
                                                int* __restrict__ edge_src, int E) {
    int i = blockIdx.x * 256 + threadIdx.x;
    if (i >= E) return;
    int d = dst[i];
    int pos = atomicAdd(&cursor[d], 1);
    edge_src[pos] = src[i];
}

// ---------------------------------------------------------------------------
// Kernel: gather-aggregate. One wave per node:
//   agg[d,:] = (1+eps)*x[d,:] + sum_{s in adj(d)} x[s,:]
// lane handles float2 -> 64 lanes * 8B = full 512B row, coalesced.
// ---------------------------------------------------------------------------
__global__ __launch_bounds__(256) void gather_agg(const float* __restrict__ x,
                                                  const float* __restrict__ epsp,
                                                  const int* __restrict__ row_ptr,
                                                  const int* __restrict__ edge_src,
                                                  float* __restrict__ agg, int N) {
    int wid = (blockIdx.x * 256 + (int)threadIdx.x) >> 6;
    int lane = threadIdx.x & 63;
    if (wid >= N) return;
    int beg = row_ptr[wid];
    int end = row_ptr[wid + 1];
    size_t off = (size_t)lane * 2;
    float ax = 0.f, ay = 0.f;
    int j = beg;
    for (; j + 1 < end; j += 2) {
        int s0 = edge_src[j];
        int s1 = edge_src[j + 1];
        float2 v0 = *reinterpret_cast<const float2*>(x + (size_t)s0 * F_IN + off);
        float2 v1 = *reinterpret_cast<const float2*>(x + (size_t)s1 * F_IN + off);
        ax += v0.x + v1.x;
        ay += v0.y + v1.y;
    }
    if (j < end) {
        int s = edge_src[j];
        float2 v = *reinterpret_cast<const float2*>(x + (size_t)s * F_IN + off);
        ax += v.x;
        ay += v.y;
    }
    float sc = 1.0f + epsp[0];
    float2 xv = *reinterpret_cast<const float2*>(x + (size_t)wid * F_IN + off);
    float2 o;
    o.x = fmaf(sc, xv.x, ax);
    o.y = fmaf(sc, xv.y, ay);
    *reinterpret_cast<float2*>(agg + (size_t)wid * F_IN + off) = o;
}

// ---------------------------------------------------------------------------
// Kernel: h1T[col][row] = relu(agg[row,:] @ W1[:,col] + b1[col])
// fp32 tiled GEMM: M=N(50000), K=128, N=256. BM=BN=64, BK=32, 256 thr, 4x4/thr.
// Writes TRANSPOSED output [H_DIM][N] for coalesced downstream access.
// ---------------------------------------------------------------------------
#define BM 64
#define BN 64
#define BK 32
__global__ __launch_bounds__(256) void gemm1(const float* __restrict__ A,
                                             const float* __restrict__ W1,
                                             const float* __restrict__ b1,
                                             float* __restrict__ h1T, int N) {
    __shared__ float As[BK][BM + 4];
    __shared__ float Bs[BK][BN];

    int tid = threadIdx.x;
    int tx = tid & 15;
    int ty = tid >> 4;
    int m0 = blockIdx.x * BM;
    int n0 = blockIdx.y * BN;

    float acc[4][4] = {};

    for (int k0 = 0; k0 < F_IN; k0 += BK) {
        #pragma unroll
        for (int l = 0; l < 2; ++l) {
            int i = tid + l * 256;
            int row = i >> 3;
            int c4 = i & 7;
            float4 v = make_float4(0.f, 0.f, 0.f, 0.f);
            int gr = m0 + row;
            if (gr < N) v = *reinterpret_cast<const float4*>(A + (size_t)gr * F_IN + k0 + c4 * 4);
            As[c4 * 4 + 0][row] = v.x;
            As[c4 * 4 + 1][row] = v.y;
            As[c4 * 4 + 2][row] = v.z;
            As[c4 * 4 + 3][row] = v.w;
        }
        #pragma unroll
        for (int l = 0; l < 2; ++l) {
            int i = tid + l * 256;
            int row = i >> 4;
            int c4 = i & 15;
            *reinterpret_cast<float4*>(&Bs[row][c4 * 4]) =
                *reinterpret_cast<const float4*>(W1 + (size_t)(k0 + row) * H_DIM + n0 + c4 * 4);
        }
        __syncthreads();

        #pragma unroll
        for (int k = 0; k < BK; ++k) {
            float4 a4 = *reinterpret_cast<const float4*>(&As[k][ty * 4]);
            float4 b4 = *reinterpret_cast<const float4*>(&Bs[k][tx * 4]);
            float a[4] = {a4.x, a4.y, a4.z, a4.w};
            float b[4] = {b4.x, b4.y, b4.z, b4.w};
            #pragma unroll
            for (int r = 0; r < 4; ++r)
                #pragma unroll
                for (int c = 0; c < 4; ++c)
                    acc[r][c] = fmaf(a[r], b[c], acc[r][c]);
        }
        __syncthreads();
    }

    float4 bias = *reinterpret_cast<const float4*>(b1 + n0 + tx * 4);
    float bv[4] = {bias.x, bias.y, bias.z, bias.w};
    int row0 = m0 + ty * 4;
    #pragma unroll
    for (int c = 0; c < 4; ++c) {
        float4 v;
        v.x = fmaxf(acc[0][c] + bv[c], 0.f);
        v.y = fmaxf(acc[1][c] + bv[c], 0.f);
        v.z = fmaxf(acc[2][c] + bv[c], 0.f);
        v.w = fmaxf(acc[3][c] + bv[c], 0.f);
        size_t base = (size_t)(n0 + tx * 4 + c) * N;
        if (row0 + 3 < N) {
            *reinterpret_cast<float4*>(h1T + base + row0) = v;
        } else {
            float vv[4] = {v.x, v.y, v.z, v.w};
            for (int r = 0; r < 4; ++r)
                if (row0 + r < N) h1T[base + row0 + r] = vv[r];
        }
    }
}

// ---------------------------------------------------------------------------
// Kernel: per-column sum & sumsq over N rows (one block per hidden column)
// ---------------------------------------------------------------------------
__global__ __launch_bounds__(256) void bn_stats(const float* __restrict__ h1T,
                                                float* __restrict__ sums,
                                                float* __restrict__ sumsq, int N) {
    __shared__ float red[8];
    int k = blockIdx.x;
    const float* col = h1T + (size_t)k * N;
    float s = 0.f, ss = 0.f;
    for (int i = threadIdx.x; i < N; i += 256) {
        float v = col[i];
        s += v;
        ss = fmaf(v, v, ss);
    }
    #pragma unroll
    for (int off = 32; off > 0; off >>= 1) {
        s += __shfl_down(s, off, 64);
        ss += __shfl_down(ss, off, 64);
    }
    int wave = threadIdx.x >> 6;
    int lane = threadIdx.x & 63;
    if (lane == 0) { red[wave] = s; red[4 + wave] = ss; }
    __syncthreads();
    if (threadIdx.x == 0) {
        sums[k] = red[0] + red[1] + red[2] + red[3];
        sumsq[k] = red[4] + red[5] + red[6] + red[7];
    }
}

// ---------------------------------------------------------------------------
// Kernel: fold BN into W2/b2:  W2f = scale*W2 ; b2f = b2 + shift @ W2
// ---------------------------------------------------------------------------
__global__ __launch_bounds__(256) void bn_fold(const float* __restrict__ sums,
                                               const float* __restrict__ sumsq,
                                               const float* __restrict__ gamma,
                                               const float* __restrict__ beta,
                                               const float* __restrict__ W2,
                                               const float* __restrict__ b2,
                                               float* __restrict__ W2f,
                                               float* __restrict__ b2f, int N) {
    __shared__ float shift_s[H_DIM];
    int k = threadIdx.x;
    float invN = 1.0f / (float)N;
    float mean = sums[k] * invN;
    float var = sumsq[k] * invN - mean * mean;
    float scale = gamma[k] * rsqrtf(var + 1e-5f);
    float shift = beta[k] - mean * scale;
    shift_s[k] = shift;
    #pragma unroll
    for (int c = 0; c < C_OUT; ++c) W2f[k * C_OUT + c] = scale * W2[k * C_OUT + c];
    __syncthreads();
    if (k < C_OUT) {
        float acc = b2[k];
        for (int j = 0; j < H_DIM; ++j) acc = fmaf(shift_s[j], W2[j * C_OUT + k], acc);
        b2f[k] = acc;
    }
}

// ---------------------------------------------------------------------------
// Kernel: out[row,:] = log_softmax(h1T[:,row] @ W2f + b2f)
// ---------------------------------------------------------------------------
__global__ __launch_bounds__(64) void gemm2_lsm(const float* __restrict__ h1T,
                                                const float* __restrict__ W2f,
                                                const float* __restrict__ b2f,
                                                float* __restrict__ out, int N) {
    int row = blockIdx.x * 64 + threadIdx.x;
    int r = row < N ? row : N - 1;
    float acc[C_OUT];
    #pragma unroll
    for (int c = 0; c < C_OUT; ++c) acc[c] = b2f[c];

    const float* hp = h1T + r;
    for (int k = 0; k < H_DIM; k += 8) {
        float h[8];
        #pragma unroll
        for (int kk = 0; kk < 8; ++kk) h[kk] = hp[(size_t)(k + kk) * N];
        #pragma unroll
        for (int kk = 0; kk < 8; ++kk) {
            const float4* w = reinterpret_cast<const float4*>(W2f + (k + kk) * C_OUT);
            #pragma unroll
            for (int q = 0; q < 10; ++q) {
                float4 wv = w[q];
                acc[q * 4 + 0] = fmaf(h[kk], wv.x, acc[q * 4 + 0]);
                acc[q * 4 + 1] = fmaf(h[kk], wv.y, acc[q * 4 + 1]);
                acc[q * 4 + 2] = fmaf(h[kk], wv.z, acc[q * 4 + 2]);
                acc[q * 4 + 3] = fmaf(h[kk], wv.w, acc[q * 4 + 3]);
            }
        }
    }
    float m = acc[0];
    #pragma unroll
    for (int c = 1; c < C_OUT; ++c) m = fmaxf(m, acc[c]);
    float s = 0.f;
    #pragma unroll
    for (int c = 0; c < C_OUT; ++c) s += __expf(acc[c] - m);
    float lse = m + __logf(s);
    if (row < N) {
        float4* op = reinterpret_cast<float4*>(out + (size_t)row * C_OUT);
        #pragma unroll
        for (int q = 0; q < 10; ++q) {
            op[q] = make_float4(acc[q * 4 + 0] - lse, acc[q * 4 + 1] - lse,
                                acc[q * 4 + 2] - lse, acc[q * 4 + 3] - lse);
        }
    }
}

// ---------------------------------------------------------------------------
extern "C" void kernel_launch(void* const* d_in, const int* in_sizes, int n_in,
                              void* d_out, int out_size, void* d_ws, size_t ws_size,
                              hipStream_t stream) {
    const float* x     = (const float*)d_in[0];
    const int*   ei    = (const int*)d_in[1];
    const float* eps   = (const float*)d_in[2];
    const float* W1    = (const float*)d_in[3];
    const float* b1    = (const float*)d_in[4];
    const float* gamma = (const float*)d_in[5];
    const float* beta  = (const float*)d_in[6];
    const float* W2    = (const float*)d_in[7];
    const float* b2    = (const float*)d_in[8];
    float* out = (float*)d_out;

    int N = in_sizes[0] / F_IN;   // 50000
    int E = in_sizes[1] / 2;      // 800000
    const int* srcIdx = ei;       // edge_index[0]
    const int* dstIdx = ei + E;   // edge_index[1]

    float* ws    = (float*)d_ws;
    float* agg   = ws;                                  // N*128
    float* h1T   = agg + (size_t)N * F_IN;              // 256*N (transposed)
    float* sums  = h1T + (size_t)H_DIM * N;             // 256
    float* sumsq = sums + H_DIM;                        // 256
    float* W2f   = sumsq + H_DIM;                       // 256*40
    float* b2f   = W2f + H_DIM * C_OUT;                 // 40

    // CSR scratch aliased into h1T's region (dead until gemm1 writes h1T).
    int* deg      = (int*)h1T;          // N
    int* cursor   = deg + N;            // N
    int* row_ptr  = cursor + N;         // N+1
    int* edge_src = row_ptr + N + 1;    // E

    hipLaunchKernelGGL(zero_int, dim3((N + 255) / 256), dim3(256), 0, stream, deg, N);
    hipLaunchKernelGGL(hist_deg, dim3((E + 255) / 256), dim3(256), 0, stream, dstIdx, deg, E);
    hipLaunchKernelGGL(scan_deg, dim3(1), dim3(1024), 0, stream, deg, row_ptr, cursor, N);
    hipLaunchKernelGGL(fill_csr, dim3((E + 255) / 256), dim3(256), 0, stream,
                       srcIdx, dstIdx, cursor, edge_src, E);
    hipLaunchKernelGGL(gather_agg, dim3((N + 3) / 4), dim3(256), 0, stream,
                       x, eps, row_ptr, edge_src, agg, N);

    dim3 g1((N + BM - 1) / BM, H_DIM / BN);
    hipLaunchKernelGGL(gemm1, g1, dim3(256), 0, stream, agg, W1, b1, h1T, N);

    hipLaunchKernelGGL(bn_stats, dim3(H_DIM), dim3(256), 0, stream, h1T, sums, sumsq, N);

    hipLaunchKernelGGL(bn_fold, dim3(1), dim3(H_DIM), 0, stream,
                       sums, sumsq, gamma, beta, W2, b2, W2f, b2f, N);

    hipLaunchKernelGGL(gemm2_lsm, dim3((N + 63) / 64), dim3(64), 0, stream, h1T, W2f, b2f, out, N);
}

// Round 3
// 267.352 us; speedup vs baseline: 5.6451x; 1.2843x over previous
//
#include <hip/hip_runtime.h>
#include <hip/hip_bf16.h>
#include <math.h>

#define F_IN 128
#define H_DIM 256
#define C_OUT 40

typedef __attribute__((ext_vector_type(8))) short short8v;
typedef __attribute__((ext_vector_type(4))) float float4v;

__device__ __forceinline__ unsigned short f2bf(float f) {
    union { float f; unsigned int u; } c; c.f = f;
    unsigned int r = (c.u + 0x7fffu + ((c.u >> 16) & 1u)) >> 16;  // RNE
    return (unsigned short)r;
}
__device__ __forceinline__ float bf2f(unsigned short u) {
    union { unsigned int u; float f; } c; c.u = ((unsigned int)u) << 16;
    return c.f;
}

// ---------------------------------------------------------------------------
// prep: [blocks 0..nA)   convert x -> x_b (bf16)
//       [block  nA]      W1 -> W1T bf16  (transposed [256][128])
//       [blocks nA+1..]  zero deg
// ---------------------------------------------------------------------------
__global__ __launch_bounds__(256) void prep(const float* __restrict__ x,
                                            const float* __restrict__ W1,
                                            unsigned short* __restrict__ x_b,
                                            unsigned short* __restrict__ w1t,
                                            int* __restrict__ deg, int N, int nA) {
    int b = blockIdx.x;
    if (b < nA) {
        long long i = ((long long)b * 256 + threadIdx.x) * 8;
        if (i + 7 < (long long)N * F_IN) {
            float4 v0 = *reinterpret_cast<const float4*>(x + i);
            float4 v1 = *reinterpret_cast<const float4*>(x + i + 4);
            short8v o;
            o[0] = (short)f2bf(v0.x); o[1] = (short)f2bf(v0.y);
            o[2] = (short)f2bf(v0.z); o[3] = (short)f2bf(v0.w);
            o[4] = (short)f2bf(v1.x); o[5] = (short)f2bf(v1.y);
            o[6] = (short)f2bf(v1.z); o[7] = (short)f2bf(v1.w);
            *reinterpret_cast<short8v*>(x_b + i) = o;
        }
    } else if (b == nA) {
        int t = threadIdx.x;  // output row of W1T == column of W1
        for (int k = 0; k < F_IN; ++k)
            w1t[t * F_IN + k] = f2bf(W1[(size_t)k * H_DIM + t]);
    } else {
        int i = (b - nA - 1) * 256 + threadIdx.x;
        if (i < N) deg[i] = 0;
    }
}

// ---------------------------------------------------------------------------
__global__ __launch_bounds__(256) void hist_deg(const int* __restrict__ dst,
                                                int* __restrict__ deg, int E) {
    int i = blockIdx.x * 256 + threadIdx.x;
    if (i < E) atomicAdd(&deg[dst[i]], 1);
}

// ---------------------------------------------------------------------------
// single-block exclusive scan of deg -> row_ptr (N+1) and cursor (N)
// ---------------------------------------------------------------------------
__global__ __launch_bounds__(1024) void scan_deg(const int* __restrict__ deg,
                                                 int* __restrict__ row_ptr,
                                                 int* __restrict__ cursor, int N) {
    __shared__ int wsum[16];
    __shared__ int s_carry;
    if (threadIdx.x == 0) { s_carry = 0; row_ptr[0] = 0; }
    __syncthreads();
    int lane = threadIdx.x & 63;
    int wv = threadIdx.x >> 6;
    for (int base = 0; base < N; base += 4096) {
        int i0 = base + (int)threadIdx.x * 4;
        int4 v = make_int4(0, 0, 0, 0);
        if (i0 + 3 < N) {
            v = *reinterpret_cast<const int4*>(deg + i0);
        } else {
            if (i0 + 0 < N) v.x = deg[i0 + 0];
            if (i0 + 1 < N) v.y = deg[i0 + 1];
            if (i0 + 2 < N) v.z = deg[i0 + 2];
            if (i0 + 3 < N) v.w = deg[i0 + 3];
        }
        int tsum = v.x + v.y + v.z + v.w;
        int sc = tsum;
        #pragma unroll
        for (int o = 1; o < 64; o <<= 1) {
            int t = __shfl_up(sc, o, 64);
            if (lane >= o) sc += t;
        }
        if (lane == 63) wsum[wv] = sc;
        __syncthreads();
        if (threadIdx.x < 16) {
            int s = wsum[threadIdx.x];
            #pragma unroll
            for (int o = 1; o < 16; o <<= 1) {
                int t = __shfl_up(s, o, 16);
                if ((int)threadIdx.x >= o) s += t;
            }
            wsum[threadIdx.x] = s;
        }
        __syncthreads();
        int carry = s_carry;
        int woff = (wv > 0) ? wsum[wv - 1] : 0;
        int p0 = carry + woff + sc - tsum;
        int q0 = p0 + v.x;
        int q1 = q0 + v.y;
        int q2 = q1 + v.z;
        int q3 = q2 + v.w;
        if (i0 < N) {
            if (i0 + 3 < N) {
                *reinterpret_cast<int4*>(cursor + i0) = make_int4(p0, q0, q1, q2);
            } else {
                cursor[i0] = p0;
                if (i0 + 1 < N) cursor[i0 + 1] = q0;
                if (i0 + 2 < N) cursor[i0 + 2] = q1;
            }
            if (i0 + 0 < N) row_ptr[i0 + 1] = q0;
            if (i0 + 1 < N) row_ptr[i0 + 2] = q1;
            if (i0 + 2 < N) row_ptr[i0 + 3] = q2;
            if (i0 + 3 < N) row_ptr[i0 + 4] = q3;
        }
        int chunk_total = wsum[15];
        __syncthreads();
        if (threadIdx.x == 0) s_carry = carry + chunk_total;
        __syncthreads();
    }
}

// ---------------------------------------------------------------------------
__global__ __launch_bounds__(256) void fill_csr(const int* __restrict__ src,
                                                const int* __restrict__ dst,
                                                int* __restrict__ cursor,
                                                int* __restrict__ edge_src, int E) {
    int i = blockIdx.x * 256 + threadIdx.x;
    if (i >= E) return;
    int d = dst[i];
    int pos = atomicAdd(&cursor[d], 1);
    edge_src[pos] = src[i];
}

// ---------------------------------------------------------------------------
// gather-aggregate in bf16: agg_b[d,:] = bf16( (1+eps)*x[d,:] + sum x[s,:] )
// one wave per node, lane handles 2 bf16 (one uint) -> 256B/row coalesced
// ---------------------------------------------------------------------------
__global__ __launch_bounds__(256) void gather_agg(const unsigned int* __restrict__ xb32,
                                                  const float* __restrict__ epsp,
                                                  const int* __restrict__ row_ptr,
                                                  const int* __restrict__ edge_src,
                                                  unsigned int* __restrict__ aggb32, int N) {
    int wid = (blockIdx.x * 256 + (int)threadIdx.x) >> 6;
    int lane = threadIdx.x & 63;
    if (wid >= N) return;
    int beg = row_ptr[wid];
    int end = row_ptr[wid + 1];
    float ax = 0.f, ay = 0.f;
    int j = beg;
    for (; j + 1 < end; j += 2) {
        int s0 = edge_src[j];
        int s1 = edge_src[j + 1];
        unsigned int u0 = xb32[(size_t)s0 * 64 + lane];
        unsigned int u1 = xb32[(size_t)s1 * 64 + lane];
        ax += bf2f((unsigned short)(u0 & 0xffff)) + bf2f((unsigned short)(u1 & 0xffff));
        ay += bf2f((unsigned short)(u0 >> 16)) + bf2f((unsigned short)(u1 >> 16));
    }
    if (j < end) {
        unsigned int u = xb32[(size_t)edge_src[j] * 64 + lane];
        ax += bf2f((unsigned short)(u & 0xffff));
        ay += bf2f((unsigned short)(u >> 16));
    }
    float sc = 1.0f + epsp[0];
    unsigned int ux = xb32[(size_t)wid * 64 + lane];
    float ox = fmaf(sc, bf2f((unsigned short)(ux & 0xffff)), ax);
    float oy = fmaf(sc, bf2f((unsigned short)(ux >> 16)), ay);
    aggb32[(size_t)wid * 64 + lane] = (unsigned int)f2bf(ox) | ((unsigned int)f2bf(oy) << 16);
}

// ---------------------------------------------------------------------------
// gemm1 MFMA bf16: h1T[col][row] = bf16(relu(agg[row,:] @ W1[:,col] + b1[col]))
// block = 256 thr (4 waves, 2x2), tile 128x64, full K=128 staged in LDS.
// ---------------------------------------------------------------------------
__global__ __launch_bounds__(256) void gemm1_mfma(const unsigned short* __restrict__ agg_b,
                                                  const unsigned short* __restrict__ w1t,
                                                  const float* __restrict__ b1,
                                                  unsigned short* __restrict__ h1T, int N) {
    __shared__ short As[128][136];   // A tile, padded: 2-way max bank conflict
    __shared__ short Bs[64][136];    // W1T tile (row = output col)

    int tid = threadIdx.x;
    int m0 = blockIdx.x * 128;
    int n0 = blockIdx.y * 64;

    #pragma unroll
    for (int i = 0; i < 8; ++i) {
        int c = tid + i * 256;          // 0..2047
        int row = c >> 4, ck = c & 15;
        int gr = m0 + row;
        short8v v = {0, 0, 0, 0, 0, 0, 0, 0};
        if (gr < N) v = *reinterpret_cast<const short8v*>(agg_b + (size_t)gr * F_IN + ck * 8);
        *reinterpret_cast<short8v*>(&As[row][ck * 8]) = v;
    }
    #pragma unroll
    for (int i = 0; i < 4; ++i) {
        int c = tid + i * 256;          // 0..1023
        int row = c >> 4, ck = c & 15;
        *reinterpret_cast<short8v*>(&Bs[row][ck * 8]) =
            *reinterpret_cast<const short8v*>(w1t + (size_t)(n0 + row) * F_IN + ck * 8);
    }
    __syncthreads();

    int w = tid >> 6, lane = tid & 63;
    int wm = w >> 1, wn = w & 1;
    int lr = lane & 15, lk = (lane >> 4) * 8;

    float4v acc[4][2] = {};
    #pragma unroll
    for (int ks = 0; ks < 4; ++ks) {
        int k0 = ks * 32 + lk;
        short8v a[4], b[2];
        #pragma unroll
        for (int am = 0; am < 4; ++am)
            a[am] = *reinterpret_cast<short8v*>(&As[wm * 64 + am * 16 + lr][k0]);
        #pragma unroll
        for (int bn = 0; bn < 2; ++bn)
            b[bn] = *reinterpret_cast<short8v*>(&Bs[wn * 32 + bn * 16 + lr][k0]);
        #pragma unroll
        for (int am = 0; am < 4; ++am)
            #pragma unroll
            for (int bn = 0; bn < 2; ++bn)
                acc[am][bn] = __builtin_amdgcn_mfma_f32_16x16x32_bf16(a[am], b[bn], acc[am][bn], 0, 0, 0);
    }

    __syncthreads();  // done reading As; reuse as transpose buffer [64][136]
    short (*T)[136] = As;
    #pragma unroll
    for (int bn = 0; bn < 2; ++bn) {
        int col = wn * 32 + bn * 16 + lr;
        float bias = b1[n0 + col];
        #pragma unroll
        for (int am = 0; am < 4; ++am) {
            #pragma unroll
            for (int r = 0; r < 4; ++r) {
                int rowl = wm * 64 + am * 16 + (lane >> 4) * 4 + r;
                float v = fmaxf(acc[am][bn][r] + bias, 0.f);
                T[col][rowl] = (short)f2bf(v);
            }
        }
    }
    __syncthreads();

    #pragma unroll
    for (int i = 0; i < 4; ++i) {
        int c = tid + i * 256;          // 0..1023 : 64 cols x 16 chunks
        int col = c >> 4, ck = c & 15;
        int gr0 = m0 + ck * 8;
        size_t base = (size_t)(n0 + col) * N;
        if (gr0 + 7 < N) {
            *reinterpret_cast<short8v*>(h1T + base + gr0) =
                *reinterpret_cast<short8v*>(&T[col][ck * 8]);
        } else {
            for (int e = 0; e < 8; ++e)
                if (gr0 + e < N) h1T[base + gr0 + e] = (unsigned short)T[col][ck * 8 + e];
        }
    }
}

// ---------------------------------------------------------------------------
// per-column sum & sumsq over N rows (bf16 input)
// ---------------------------------------------------------------------------
__global__ __launch_bounds__(256) void bn_stats(const unsigned short* __restrict__ h1T,
                                                float* __restrict__ sums,
                                                float* __restrict__ sumsq, int N) {
    __shared__ float red[8];
    int k = blockIdx.x;
    const unsigned short* col = h1T + (size_t)k * N;
    float s = 0.f, ss = 0.f;
    for (int i = threadIdx.x * 8; i + 7 < N; i += 256 * 8) {
        short8v v = *reinterpret_cast<const short8v*>(col + i);
        #pragma unroll
        for (int e = 0; e < 8; ++e) {
            float f = bf2f((unsigned short)v[e]);
            s += f;
            ss = fmaf(f, f, ss);
        }
    }
    // tail (N not multiple of 2048 handled: elements >= 8*floor stride covered above only
    // when i+7<N; catch remaining scalars)
    int tail_start = (N / 8) * 8;
    for (int i = tail_start + threadIdx.x; i < N; i += 256) {
        float f = bf2f(col[i]);
        s += f;
        ss = fmaf(f, f, ss);
    }
    #pragma unroll
    for (int off = 32; off > 0; off >>= 1) {
        s += __shfl_down(s, off, 64);
        ss += __shfl_down(ss, off, 64);
    }
    int wave = threadIdx.x >> 6;
    int lane = threadIdx.x & 63;
    if (lane == 0) { red[wave] = s; red[4 + wave] = ss; }
    __syncthreads();
    if (threadIdx.x == 0) {
        sums[k] = red[0] + red[1] + red[2] + red[3];
        sumsq[k] = red[4] + red[5] + red[6] + red[7];
    }
}

// ---------------------------------------------------------------------------
// fold BN into W2/b2 (fp32)
// ---------------------------------------------------------------------------
__global__ __launch_bounds__(256) void bn_fold(const float* __restrict__ sums,
                                               const float* __restrict__ sumsq,
                                               const float* __restrict__ gamma,
                                               const float* __restrict__ beta,
                                               const float* __restrict__ W2,
                                               const float* __restrict__ b2,
                                               float* __restrict__ W2f,
                                               float* __restrict__ b2f, int N) {
    __shared__ float shift_s[H_DIM];
    int k = threadIdx.x;
    float invN = 1.0f / (float)N;
    float mean = sums[k] * invN;
    float var = sumsq[k] * invN - mean * mean;
    float scale = gamma[k] * rsqrtf(var + 1e-5f);
    float shift = beta[k] - mean * scale;
    shift_s[k] = shift;
    #pragma unroll
    for (int c = 0; c < C_OUT; ++c) W2f[k * C_OUT + c] = scale * W2[k * C_OUT + c];
    __syncthreads();
    if (k < C_OUT) {
        float acc = b2[k];
        for (int j = 0; j < H_DIM; ++j) acc = fmaf(shift_s[j], W2[j * C_OUT + k], acc);
        b2f[k] = acc;
    }
}

// ---------------------------------------------------------------------------
// out[row,:] = log_softmax(h1(row,:) @ W2f + b2f), h1 read from bf16 h1T
// ---------------------------------------------------------------------------
__global__ __launch_bounds__(256) void gemm2_lsm(const unsigned short* __restrict__ h1T,
                                                 const float* __restrict__ W2f,
                                                 const float* __restrict__ b2f,
                                                 float* __restrict__ out, int N) {
    int row = blockIdx.x * 256 + threadIdx.x;
    int r = row < N ? row : N - 1;
    float acc[C_OUT];
    #pragma unroll
    for (int c = 0; c < C_OUT; ++c) acc[c] = b2f[c];

    const unsigned short* hp = h1T + r;
    for (int k = 0; k < H_DIM; k += 8) {
        float h[8];
        #pragma unroll
        for (int kk = 0; kk < 8; ++kk) h[kk] = bf2f(hp[(size_t)(k + kk) * N]);
        #pragma unroll
        for (int kk = 0; kk < 8; ++kk) {
            const float4* wv4 = reinterpret_cast<const float4*>(W2f + (k + kk) * C_OUT);
            #pragma unroll
            for (int q = 0; q < 10; ++q) {
                float4 wv = wv4[q];
                acc[q * 4 + 0] = fmaf(h[kk], wv.x, acc[q * 4 + 0]);
                acc[q * 4 + 1] = fmaf(h[kk], wv.y, acc[q * 4 + 1]);
                acc[q * 4 + 2] = fmaf(h[kk], wv.z, acc[q * 4 + 2]);
                acc[q * 4 + 3] = fmaf(h[kk], wv.w, acc[q * 4 + 3]);
            }
        }
    }
    float m = acc[0];
    #pragma unroll
    for (int c = 1; c < C_OUT; ++c) m = fmaxf(m, acc[c]);
    float s = 0.f;
    #pragma unroll
    for (int c = 0; c < C_OUT; ++c) s += __expf(acc[c] - m);
    float lse = m + __logf(s);
    if (row < N) {
        float4* op = reinterpret_cast<float4*>(out + (size_t)row * C_OUT);
        #pragma unroll
        for (int q = 0; q < 10; ++q) {
            op[q] = make_float4(acc[q * 4 + 0] - lse, acc[q * 4 + 1] - lse,
                                acc[q * 4 + 2] - lse, acc[q * 4 + 3] - lse);
        }
    }
}

// ---------------------------------------------------------------------------
extern "C" void kernel_launch(void* const* d_in, const int* in_sizes, int n_in,
                              void* d_out, int out_size, void* d_ws, size_t ws_size,
                              hipStream_t stream) {
    const float* x     = (const float*)d_in[0];
    const int*   ei    = (const int*)d_in[1];
    const float* eps   = (const float*)d_in[2];
    const float* W1    = (const float*)d_in[3];
    const float* b1    = (const float*)d_in[4];
    const float* gamma = (const float*)d_in[5];
    const float* beta  = (const float*)d_in[6];
    const float* W2    = (const float*)d_in[7];
    const float* b2    = (const float*)d_in[8];
    float* out = (float*)d_out;

    int N = in_sizes[0] / F_IN;   // 50000
    int E = in_sizes[1] / 2;      // 800000
    const int* srcIdx = ei;
    const int* dstIdx = ei + E;

    // workspace layout (bf16-heavy)
    unsigned short* x_b   = (unsigned short*)d_ws;                 // N*128
    unsigned short* agg_b = x_b + (size_t)N * F_IN;                // N*128
    unsigned short* w1t   = agg_b + (size_t)N * F_IN;              // 256*128
    unsigned short* h1T   = w1t + H_DIM * F_IN;                    // 256*N
    float* sums  = (float*)(h1T + (size_t)H_DIM * N);              // 256
    float* sumsq = sums + H_DIM;                                   // 256
    float* W2f   = sumsq + H_DIM;                                  // 256*40
    float* b2f   = W2f + H_DIM * C_OUT;                            // 40

    // CSR scratch aliased into h1T region (dead before gemm1 writes h1T)
    int* deg      = (int*)h1T;          // N
    int* cursor   = deg + N;            // N
    int* row_ptr  = cursor + N;         // N+1
    int* edge_src = row_ptr + N + 1;    // E

    int nA = (N * 16 + 255) / 256;        // blocks for x conversion (8 elems/thread)
    int nZ = (N + 255) / 256;             // blocks for deg zeroing
    hipLaunchKernelGGL(prep, dim3(nA + 1 + nZ), dim3(256), 0, stream,
                       x, W1, x_b, w1t, deg, N, nA);

    hipLaunchKernelGGL(hist_deg, dim3((E + 255) / 256), dim3(256), 0, stream, dstIdx, deg, E);
    hipLaunchKernelGGL(scan_deg, dim3(1), dim3(1024), 0, stream, deg, row_ptr, cursor, N);
    hipLaunchKernelGGL(fill_csr, dim3((E + 255) / 256), dim3(256), 0, stream,
                       srcIdx, dstIdx, cursor, edge_src, E);

    hipLaunchKernelGGL(gather_agg, dim3((N * 64 + 255) / 256), dim3(256), 0, stream,
                       (const unsigned int*)x_b, eps, row_ptr, edge_src,
                       (unsigned int*)agg_b, N);

    dim3 g1((N + 127) / 128, H_DIM / 64);
    hipLaunchKernelGGL(gemm1_mfma, g1, dim3(256), 0, stream, agg_b, w1t, b1, h1T, N);

    hipLaunchKernelGGL(bn_stats, dim3(H_DIM), dim3(256), 0, stream, h1T, sums, sumsq, N);

    hipLaunchKernelGGL(bn_fold, dim3(1), dim3(H_DIM), 0, stream,
                       sums, sumsq, gamma, beta, W2, b2, W2f, b2f, N);

    hipLaunchKernelGGL(gemm2_lsm, dim3((N + 255) / 256), dim3(256), 0, stream,
                       h1T, W2f, b2f, out, N);
}